// Round 1
// baseline (227.607 us; speedup 1.0000x reference)
//
#include <hip/hip_runtime.h>

#define M_DIM 8192
#define N_DIM 2048
#define K_DIM 2048

#define BM 128
#define BN 128
#define BK 32

#define AS1 __attribute__((address_space(1)))
#define AS3 __attribute__((address_space(3)))

typedef float f32x4 __attribute__((ext_vector_type(4)));
typedef short s16x8 __attribute__((ext_vector_type(8)));

__device__ __forceinline__ unsigned short f2bf(float f) {
  unsigned int u = __float_as_uint(f);
  u += 0x7FFFu + ((u >> 16) & 1u);   // round-to-nearest-even
  return (unsigned short)(u >> 16);
}

// ---------------------------------------------------------------------------
// Kernel 1: per-token asymmetric int8 fake-quant, output bf16 x_dq [M][K]
// ---------------------------------------------------------------------------
__global__ __launch_bounds__(256) void quant_x_kernel(
    const float* __restrict__ x, unsigned short* __restrict__ A) {
  const int t   = blockIdx.x;
  const int tid = threadIdx.x;
  const float4* r4 = (const float4*)(x + (size_t)t * K_DIM);
  float4 v0 = r4[tid];
  float4 v1 = r4[tid + 256];

  float mn = fminf(fminf(fminf(v0.x, v0.y), fminf(v0.z, v0.w)),
                   fminf(fminf(v1.x, v1.y), fminf(v1.z, v1.w)));
  float mx = fmaxf(fmaxf(fmaxf(v0.x, v0.y), fmaxf(v0.z, v0.w)),
                   fmaxf(fmaxf(v1.x, v1.y), fmaxf(v1.z, v1.w)));
#pragma unroll
  for (int off = 32; off > 0; off >>= 1) {
    mn = fminf(mn, __shfl_xor(mn, off));
    mx = fmaxf(mx, __shfl_xor(mx, off));
  }
  __shared__ float smn[4], smx[4];
  if ((tid & 63) == 0) { smn[tid >> 6] = mn; smx[tid >> 6] = mx; }
  __syncthreads();
  mn = fminf(fminf(smn[0], smn[1]), fminf(smn[2], smn[3]));
  mx = fmaxf(fmaxf(smx[0], smx[1]), fmaxf(smx[2], smx[3]));
  mn = fminf(mn, 0.0f);
  mx = fmaxf(mx, 0.0f);

  float scale = (mx - mn) / 255.0f;                 // (QMAX-QMIN)=255
  scale = fmaxf(scale, 1.1920928955078125e-07f);    // f32 eps = 2^-23
  float zp = -128.0f - rintf(mn / scale);
  zp = fminf(fmaxf(zp, -128.0f), 127.0f);

  ushort4* Ao = (ushort4*)(A + (size_t)t * K_DIM);
  {
    float q; ushort4 r;
    q = rintf(v0.x / scale) + zp; q = fminf(fmaxf(q, -128.f), 127.f); r.x = f2bf((q - zp) * scale);
    q = rintf(v0.y / scale) + zp; q = fminf(fmaxf(q, -128.f), 127.f); r.y = f2bf((q - zp) * scale);
    q = rintf(v0.z / scale) + zp; q = fminf(fmaxf(q, -128.f), 127.f); r.z = f2bf((q - zp) * scale);
    q = rintf(v0.w / scale) + zp; q = fminf(fmaxf(q, -128.f), 127.f); r.w = f2bf((q - zp) * scale);
    Ao[tid] = r;
  }
  {
    float q; ushort4 r;
    q = rintf(v1.x / scale) + zp; q = fminf(fmaxf(q, -128.f), 127.f); r.x = f2bf((q - zp) * scale);
    q = rintf(v1.y / scale) + zp; q = fminf(fmaxf(q, -128.f), 127.f); r.y = f2bf((q - zp) * scale);
    q = rintf(v1.z / scale) + zp; q = fminf(fmaxf(q, -128.f), 127.f); r.z = f2bf((q - zp) * scale);
    q = rintf(v1.w / scale) + zp; q = fminf(fmaxf(q, -128.f), 127.f); r.w = f2bf((q - zp) * scale);
    Ao[tid + 256] = r;
  }
}

// ---------------------------------------------------------------------------
// Kernel 2: grouped int4 dequant of W -> bf16 w_dq [N][K]
// ---------------------------------------------------------------------------
__global__ __launch_bounds__(256) void prep_w_kernel(
    const int* __restrict__ w, const float* __restrict__ ws,
    const float* __restrict__ wz, unsigned short* __restrict__ W) {
  const int idx = blockIdx.x * 256 + threadIdx.x;  // one 8-elem chunk
  const int o  = idx >> 8;                         // 2048/8 = 256 chunks/row
  const int ii = (idx & 255) * 8;
  const int g  = ii >> 5;                          // GROUPSIZE=32, 8|32
  const float s = ws[o * 64 + g];
  const float z = wz[o * 64 + g];
  const int4* wp = (const int4*)(w + (size_t)o * K_DIM + ii);
  int4 a = wp[0], b = wp[1];
  ushort4 r0, r1;
  r0.x = f2bf(((float)a.x - z) * s);
  r0.y = f2bf(((float)a.y - z) * s);
  r0.z = f2bf(((float)a.z - z) * s);
  r0.w = f2bf(((float)a.w - z) * s);
  r1.x = f2bf(((float)b.x - z) * s);
  r1.y = f2bf(((float)b.y - z) * s);
  r1.z = f2bf(((float)b.z - z) * s);
  r1.w = f2bf(((float)b.w - z) * s);
  ushort4* Wo = (ushort4*)(W + (size_t)o * K_DIM + ii);
  Wo[0] = r0;
  Wo[1] = r1;
}

// ---------------------------------------------------------------------------
// Kernel 3: C[M][N] = A[M][K] * B[N][K]^T, bf16 in, f32 out (m97 structure)
// ---------------------------------------------------------------------------
__global__ __launch_bounds__(256) void gemm_kernel(
    const unsigned short* __restrict__ A,
    const unsigned short* __restrict__ B,
    float* __restrict__ C) {
  __shared__ unsigned short As[BM * BK];  // 8 KB
  __shared__ unsigned short Bs[BN * BK];  // 8 KB

  const int tid  = threadIdx.x;
  const int bm   = blockIdx.y * BM;
  const int bn   = blockIdx.x * BN;
  const int lane = tid & 63;
  const int wv   = tid >> 6;
  const int waveM = (wv >> 1) * 64;
  const int waveN = (wv & 1) * 64;
  const int quad = lane >> 4;
  const int l16  = lane & 15;

  // --- staging coords: thread covers 16B; XOR swizzle of k-chunk within row
  const int srow0 = tid >> 2;        // rows 0..63   (issue 0)
  const int srow1 = 64 + (tid >> 2); // rows 64..127 (issue 1)
  const int kcp   = tid & 3;         // physical 16B chunk within 64B row
  const int kc0   = kcp ^ ((srow0 >> 1) & 3);
  const int kc1   = kcp ^ ((srow1 >> 1) & 3);

  const unsigned short* ag0 = A + (size_t)(bm + srow0) * K_DIM + kc0 * 8;
  const unsigned short* ag1 = A + (size_t)(bm + srow1) * K_DIM + kc1 * 8;
  const unsigned short* bg0 = B + (size_t)(bn + srow0) * K_DIM + kc0 * 8;
  const unsigned short* bg1 = B + (size_t)(bn + srow1) * K_DIM + kc1 * 8;

  unsigned short* la0 = &As[tid * 8];
  unsigned short* la1 = &As[2048 + tid * 8];
  unsigned short* lb0 = &Bs[tid * 8];
  unsigned short* lb1 = &Bs[2048 + tid * 8];

  // --- fragment read offsets (undo the swizzle)
  int aoff[4], boff[4];
#pragma unroll
  for (int i = 0; i < 4; ++i) {
    int ra = waveM + i * 16 + l16;
    aoff[i] = ra * BK + (quad ^ ((ra >> 1) & 3)) * 8;
    int rb = waveN + i * 16 + l16;
    boff[i] = rb * BK + (quad ^ ((rb >> 1) & 3)) * 8;
  }

  f32x4 acc[4][4] = {};

  for (int k0 = 0; k0 < K_DIM; k0 += BK) {
    __builtin_amdgcn_global_load_lds((const AS1 void*)(ag0 + k0), (AS3 void*)la0, 16, 0, 0);
    __builtin_amdgcn_global_load_lds((const AS1 void*)(ag1 + k0), (AS3 void*)la1, 16, 0, 0);
    __builtin_amdgcn_global_load_lds((const AS1 void*)(bg0 + k0), (AS3 void*)lb0, 16, 0, 0);
    __builtin_amdgcn_global_load_lds((const AS1 void*)(bg1 + k0), (AS3 void*)lb1, 16, 0, 0);
    __syncthreads();  // compiler emits vmcnt(0) drain before s_barrier

    s16x8 af[4], bf[4];
#pragma unroll
    for (int i = 0; i < 4; ++i) {
      af[i] = *(const s16x8*)&As[aoff[i]];
      bf[i] = *(const s16x8*)&Bs[boff[i]];
    }
#pragma unroll
    for (int mi = 0; mi < 4; ++mi)
#pragma unroll
      for (int ni = 0; ni < 4; ++ni)
        acc[mi][ni] = __builtin_amdgcn_mfma_f32_16x16x32_bf16(
            af[mi], bf[ni], acc[mi][ni], 0, 0, 0);
    __syncthreads();
  }

  // --- epilogue: C/D layout col=lane&15, row=quad*4+reg (m89/m91 verified)
#pragma unroll
  for (int mi = 0; mi < 4; ++mi) {
#pragma unroll
    for (int ni = 0; ni < 4; ++ni) {
      const int o = bn + waveN + ni * 16 + l16;
#pragma unroll
      for (int r = 0; r < 4; ++r) {
        const int t = bm + waveM + mi * 16 + quad * 4 + r;
        C[(size_t)t * N_DIM + o] = acc[mi][ni][r];
      }
    }
  }
}

// ---------------------------------------------------------------------------
extern "C" void kernel_launch(void* const* d_in, const int* in_sizes, int n_in,
                              void* d_out, int out_size, void* d_ws, size_t ws_size,
                              hipStream_t stream) {
  const float* x        = (const float*)d_in[0];
  const int*   w_int    = (const int*)d_in[1];
  const float* w_scales = (const float*)d_in[2];
  const float* w_zeros  = (const float*)d_in[3];
  float* out = (float*)d_out;

  unsigned short* Aq = (unsigned short*)d_ws;                 // 8192*2048 bf16
  unsigned short* Wq = Aq + (size_t)M_DIM * K_DIM;            // 2048*2048 bf16

  quant_x_kernel<<<M_DIM, 256, 0, stream>>>(x, Aq);
  prep_w_kernel<<<(N_DIM * (K_DIM / 8)) / 256, 256, 0, stream>>>(w_int, w_scales, w_zeros, Wq);
  dim3 grid(N_DIM / BN, M_DIM / BM);
  gemm_kernel<<<grid, 256, 0, stream>>>(Aq, Wq, out);
}

// Round 2
// 195.097 us; speedup vs baseline: 1.1666x; 1.1666x over previous
//
#include <hip/hip_runtime.h>

#define M_DIM 8192
#define N_DIM 2048
#define K_DIM 2048

#define BM 256
#define BN 128
#define BK 64

#define AS1 __attribute__((address_space(1)))
#define AS3 __attribute__((address_space(3)))

typedef float f32x4 __attribute__((ext_vector_type(4)));
typedef short s16x8 __attribute__((ext_vector_type(8)));

__device__ __forceinline__ unsigned short f2bf(float f) {
  unsigned int u = __float_as_uint(f);
  u += 0x7FFFu + ((u >> 16) & 1u);   // round-to-nearest-even
  return (unsigned short)(u >> 16);
}

// ---------------------------------------------------------------------------
// Kernel 1: per-token asymmetric int8 fake-quant, output bf16 x_dq [M][K]
// ---------------------------------------------------------------------------
__global__ __launch_bounds__(256) void quant_x_kernel(
    const float* __restrict__ x, unsigned short* __restrict__ A) {
  const int t   = blockIdx.x;
  const int tid = threadIdx.x;
  const float4* r4 = (const float4*)(x + (size_t)t * K_DIM);
  float4 v0 = r4[tid];
  float4 v1 = r4[tid + 256];

  float mn = fminf(fminf(fminf(v0.x, v0.y), fminf(v0.z, v0.w)),
                   fminf(fminf(v1.x, v1.y), fminf(v1.z, v1.w)));
  float mx = fmaxf(fmaxf(fmaxf(v0.x, v0.y), fmaxf(v0.z, v0.w)),
                   fmaxf(fmaxf(v1.x, v1.y), fmaxf(v1.z, v1.w)));
#pragma unroll
  for (int off = 32; off > 0; off >>= 1) {
    mn = fminf(mn, __shfl_xor(mn, off));
    mx = fmaxf(mx, __shfl_xor(mx, off));
  }
  __shared__ float smn[4], smx[4];
  if ((tid & 63) == 0) { smn[tid >> 6] = mn; smx[tid >> 6] = mx; }
  __syncthreads();
  mn = fminf(fminf(smn[0], smn[1]), fminf(smn[2], smn[3]));
  mx = fmaxf(fmaxf(smx[0], smx[1]), fmaxf(smx[2], smx[3]));
  mn = fminf(mn, 0.0f);
  mx = fmaxf(mx, 0.0f);

  float scale = (mx - mn) / 255.0f;                 // (QMAX-QMIN)=255
  scale = fmaxf(scale, 1.1920928955078125e-07f);    // f32 eps = 2^-23
  const float inv = 1.0f / scale;                   // one IEEE div per token
  float zp = -128.0f - rintf(mn * inv);
  zp = fminf(fmaxf(zp, -128.0f), 127.0f);

  ushort4* Ao = (ushort4*)(A + (size_t)t * K_DIM);
  {
    float q; ushort4 r;
    q = rintf(v0.x * inv) + zp; q = fminf(fmaxf(q, -128.f), 127.f); r.x = f2bf((q - zp) * scale);
    q = rintf(v0.y * inv) + zp; q = fminf(fmaxf(q, -128.f), 127.f); r.y = f2bf((q - zp) * scale);
    q = rintf(v0.z * inv) + zp; q = fminf(fmaxf(q, -128.f), 127.f); r.z = f2bf((q - zp) * scale);
    q = rintf(v0.w * inv) + zp; q = fminf(fmaxf(q, -128.f), 127.f); r.w = f2bf((q - zp) * scale);
    Ao[tid] = r;
  }
  {
    float q; ushort4 r;
    q = rintf(v1.x * inv) + zp; q = fminf(fmaxf(q, -128.f), 127.f); r.x = f2bf((q - zp) * scale);
    q = rintf(v1.y * inv) + zp; q = fminf(fmaxf(q, -128.f), 127.f); r.y = f2bf((q - zp) * scale);
    q = rintf(v1.z * inv) + zp; q = fminf(fmaxf(q, -128.f), 127.f); r.z = f2bf((q - zp) * scale);
    q = rintf(v1.w * inv) + zp; q = fminf(fmaxf(q, -128.f), 127.f); r.w = f2bf((q - zp) * scale);
    Ao[tid + 256] = r;
  }
}

// ---------------------------------------------------------------------------
// Kernel 2: grouped int4 dequant of W -> bf16 w_dq [N][K]
// ---------------------------------------------------------------------------
__global__ __launch_bounds__(256) void prep_w_kernel(
    const int* __restrict__ w, const float* __restrict__ ws,
    const float* __restrict__ wz, unsigned short* __restrict__ W) {
  const int idx = blockIdx.x * 256 + threadIdx.x;  // one 8-elem chunk
  const int o  = idx >> 8;                         // 2048/8 = 256 chunks/row
  const int ii = (idx & 255) * 8;
  const int g  = ii >> 5;                          // GROUPSIZE=32, 8|32
  const float s = ws[o * 64 + g];
  const float z = wz[o * 64 + g];
  const int4* wp = (const int4*)(w + (size_t)o * K_DIM + ii);
  int4 a = wp[0], b = wp[1];
  ushort4 r0, r1;
  r0.x = f2bf(((float)a.x - z) * s);
  r0.y = f2bf(((float)a.y - z) * s);
  r0.z = f2bf(((float)a.z - z) * s);
  r0.w = f2bf(((float)a.w - z) * s);
  r1.x = f2bf(((float)b.x - z) * s);
  r1.y = f2bf(((float)b.y - z) * s);
  r1.z = f2bf(((float)b.z - z) * s);
  r1.w = f2bf(((float)b.w - z) * s);
  ushort4* Wo = (ushort4*)(W + (size_t)o * K_DIM + ii);
  Wo[0] = r0;
  Wo[1] = r1;
}

// ---------------------------------------------------------------------------
// Kernel 3: C[M][N] = A[M][K] * B[N][K]^T, bf16 in, f32 out
// BM=256 BN=128 BK=64, 4 waves, wave tile 128x64 (8x4 of 16x16x32 MFMA).
// LDS-per-MFMA ratio 0.375 (vs 0.5 at 4x4); 64 MFMA per barrier-pair.
// ---------------------------------------------------------------------------
__global__ __launch_bounds__(256, 2) void gemm_kernel(
    const unsigned short* __restrict__ A,
    const unsigned short* __restrict__ B,
    float* __restrict__ C) {
  __shared__ unsigned short As[BM * BK];  // 32 KB
  __shared__ unsigned short Bs[BN * BK];  // 16 KB

  const int tid  = threadIdx.x;
  const int bm   = blockIdx.y * BM;   // gridDim.y = 32
  const int bn   = blockIdx.x * BN;   // gridDim.x = 16
  const int lane = tid & 63;
  const int wv   = tid >> 6;
  const int waveM = (wv >> 1) * 128;
  const int waveN = (wv & 1) * 64;
  const int quad = lane >> 4;
  const int l16  = lane & 15;

  // --- staging: thread covers one 16B chunk per issue.
  // row = j*32 + (tid>>3); chunk-in-row (phys, global side) = (tid&7)^(row&7)
  // LDS side stays lane-linear (wave-uniform base + lane*16) as required.
  const int trow = tid >> 3;                    // 0..31
  const int phys = (tid & 7) ^ (trow & 7);
  const unsigned short* ag = A + (size_t)(bm + trow) * K_DIM + phys * 8;
  const unsigned short* bg = B + (size_t)(bn + trow) * K_DIM + phys * 8;
  unsigned short* al = &As[tid * 8];
  unsigned short* bl = &Bs[tid * 8];

  // --- fragment read offsets (undo swizzle): slot = (kk*4+quad) ^ (row&7)
  // kk toggles slot bit2 -> offset ^ 32 (ushort units)
  int aoff[8], boff[4];
#pragma unroll
  for (int mi = 0; mi < 8; ++mi)
    aoff[mi] = (waveM + mi * 16 + l16) * BK + ((quad ^ (l16 & 7)) * 8);
#pragma unroll
  for (int ni = 0; ni < 4; ++ni)
    boff[ni] = (waveN + ni * 16 + l16) * BK + ((quad ^ (l16 & 7)) * 8);

  f32x4 acc[8][4] = {};

  for (int k0 = 0; k0 < K_DIM; k0 += BK) {
#pragma unroll
    for (int j = 0; j < 8; ++j)
      __builtin_amdgcn_global_load_lds((const AS1 void*)(ag + (size_t)j * 32 * K_DIM + k0),
                                       (AS3 void*)(al + j * 2048), 16, 0, 0);
#pragma unroll
    for (int j = 0; j < 4; ++j)
      __builtin_amdgcn_global_load_lds((const AS1 void*)(bg + (size_t)j * 32 * K_DIM + k0),
                                       (AS3 void*)(bl + j * 2048), 16, 0, 0);
    __syncthreads();

#pragma unroll
    for (int kk = 0; kk < 2; ++kk) {
      s16x8 af[8], bf[4];
#pragma unroll
      for (int mi = 0; mi < 8; ++mi)
        af[mi] = *(const s16x8*)&As[aoff[mi] ^ (kk * 32)];
#pragma unroll
      for (int ni = 0; ni < 4; ++ni)
        bf[ni] = *(const s16x8*)&Bs[boff[ni] ^ (kk * 32)];
#pragma unroll
      for (int mi = 0; mi < 8; ++mi)
#pragma unroll
        for (int ni = 0; ni < 4; ++ni)
          acc[mi][ni] = __builtin_amdgcn_mfma_f32_16x16x32_bf16(
              af[mi], bf[ni], acc[mi][ni], 0, 0, 0);
    }
    __syncthreads();
  }

  // --- epilogue: C/D layout col=lane&15, row=quad*4+reg
#pragma unroll
  for (int mi = 0; mi < 8; ++mi) {
#pragma unroll
    for (int ni = 0; ni < 4; ++ni) {
      const int o = bn + waveN + ni * 16 + l16;
#pragma unroll
      for (int r = 0; r < 4; ++r) {
        const int t = bm + waveM + mi * 16 + quad * 4 + r;
        C[(size_t)t * N_DIM + o] = acc[mi][ni][r];
      }
    }
  }
}

// ---------------------------------------------------------------------------
extern "C" void kernel_launch(void* const* d_in, const int* in_sizes, int n_in,
                              void* d_out, int out_size, void* d_ws, size_t ws_size,
                              hipStream_t stream) {
  const float* x        = (const float*)d_in[0];
  const int*   w_int    = (const int*)d_in[1];
  const float* w_scales = (const float*)d_in[2];
  const float* w_zeros  = (const float*)d_in[3];
  float* out = (float*)d_out;

  unsigned short* Aq = (unsigned short*)d_ws;                 // 8192*2048 bf16
  unsigned short* Wq = Aq + (size_t)M_DIM * K_DIM;            // 2048*2048 bf16

  quant_x_kernel<<<M_DIM, 256, 0, stream>>>(x, Aq);
  prep_w_kernel<<<(N_DIM * (K_DIM / 8)) / 256, 256, 0, stream>>>(w_int, w_scales, w_zeros, Wq);
  dim3 grid(N_DIM / BN, M_DIM / BM);
  gemm_kernel<<<grid, 256, 0, stream>>>(Aq, Wq, out);
}

// Round 3
// 194.180 us; speedup vs baseline: 1.1721x; 1.0047x over previous
//
#include <hip/hip_runtime.h>

#define M_DIM 8192
#define N_DIM 2048
#define K_DIM 2048

#define BM 256
#define BN 128
#define BK 64

#define AS1 __attribute__((address_space(1)))
#define AS3 __attribute__((address_space(3)))

typedef float f32x4 __attribute__((ext_vector_type(4)));
typedef short s16x8 __attribute__((ext_vector_type(8)));

__device__ __forceinline__ unsigned short f2bf(float f) {
  unsigned int u = __float_as_uint(f);
  u += 0x7FFFu + ((u >> 16) & 1u);   // round-to-nearest-even
  return (unsigned short)(u >> 16);
}

// ---------------------------------------------------------------------------
// Kernel 1: per-token asymmetric int8 fake-quant, output bf16 x_dq [M][K]
// ---------------------------------------------------------------------------
__global__ __launch_bounds__(256) void quant_x_kernel(
    const float* __restrict__ x, unsigned short* __restrict__ A) {
  const int t   = blockIdx.x;
  const int tid = threadIdx.x;
  const float4* r4 = (const float4*)(x + (size_t)t * K_DIM);
  float4 v0 = r4[tid];
  float4 v1 = r4[tid + 256];

  float mn = fminf(fminf(fminf(v0.x, v0.y), fminf(v0.z, v0.w)),
                   fminf(fminf(v1.x, v1.y), fminf(v1.z, v1.w)));
  float mx = fmaxf(fmaxf(fmaxf(v0.x, v0.y), fmaxf(v0.z, v0.w)),
                   fmaxf(fmaxf(v1.x, v1.y), fmaxf(v1.z, v1.w)));
#pragma unroll
  for (int off = 32; off > 0; off >>= 1) {
    mn = fminf(mn, __shfl_xor(mn, off));
    mx = fmaxf(mx, __shfl_xor(mx, off));
  }
  __shared__ float smn[4], smx[4];
  if ((tid & 63) == 0) { smn[tid >> 6] = mn; smx[tid >> 6] = mx; }
  __syncthreads();
  mn = fminf(fminf(smn[0], smn[1]), fminf(smn[2], smn[3]));
  mx = fmaxf(fmaxf(smx[0], smx[1]), fmaxf(smx[2], smx[3]));
  mn = fminf(mn, 0.0f);
  mx = fmaxf(mx, 0.0f);

  float scale = (mx - mn) / 255.0f;                 // (QMAX-QMIN)=255
  scale = fmaxf(scale, 1.1920928955078125e-07f);    // f32 eps = 2^-23
  const float inv = 1.0f / scale;                   // one IEEE div per token
  float zp = -128.0f - rintf(mn * inv);
  zp = fminf(fmaxf(zp, -128.0f), 127.0f);

  ushort4* Ao = (ushort4*)(A + (size_t)t * K_DIM);
  {
    float q; ushort4 r;
    q = rintf(v0.x * inv) + zp; q = fminf(fmaxf(q, -128.f), 127.f); r.x = f2bf((q - zp) * scale);
    q = rintf(v0.y * inv) + zp; q = fminf(fmaxf(q, -128.f), 127.f); r.y = f2bf((q - zp) * scale);
    q = rintf(v0.z * inv) + zp; q = fminf(fmaxf(q, -128.f), 127.f); r.z = f2bf((q - zp) * scale);
    q = rintf(v0.w * inv) + zp; q = fminf(fmaxf(q, -128.f), 127.f); r.w = f2bf((q - zp) * scale);
    Ao[tid] = r;
  }
  {
    float q; ushort4 r;
    q = rintf(v1.x * inv) + zp; q = fminf(fmaxf(q, -128.f), 127.f); r.x = f2bf((q - zp) * scale);
    q = rintf(v1.y * inv) + zp; q = fminf(fmaxf(q, -128.f), 127.f); r.y = f2bf((q - zp) * scale);
    q = rintf(v1.z * inv) + zp; q = fminf(fmaxf(q, -128.f), 127.f); r.z = f2bf((q - zp) * scale);
    q = rintf(v1.w * inv) + zp; q = fminf(fmaxf(q, -128.f), 127.f); r.w = f2bf((q - zp) * scale);
    Ao[tid + 256] = r;
  }
}

// ---------------------------------------------------------------------------
// Kernel 2: grouped int4 dequant of W -> bf16 w_dq [N][K]
// ---------------------------------------------------------------------------
__global__ __launch_bounds__(256) void prep_w_kernel(
    const int* __restrict__ w, const float* __restrict__ ws,
    const float* __restrict__ wz, unsigned short* __restrict__ W) {
  const int idx = blockIdx.x * 256 + threadIdx.x;  // one 8-elem chunk
  const int o  = idx >> 8;                         // 2048/8 = 256 chunks/row
  const int ii = (idx & 255) * 8;
  const int g  = ii >> 5;                          // GROUPSIZE=32, 8|32
  const float s = ws[o * 64 + g];
  const float z = wz[o * 64 + g];
  const int4* wp = (const int4*)(w + (size_t)o * K_DIM + ii);
  int4 a = wp[0], b = wp[1];
  ushort4 r0, r1;
  r0.x = f2bf(((float)a.x - z) * s);
  r0.y = f2bf(((float)a.y - z) * s);
  r0.z = f2bf(((float)a.z - z) * s);
  r0.w = f2bf(((float)a.w - z) * s);
  r1.x = f2bf(((float)b.x - z) * s);
  r1.y = f2bf(((float)b.y - z) * s);
  r1.z = f2bf(((float)b.z - z) * s);
  r1.w = f2bf(((float)b.w - z) * s);
  ushort4* Wo = (ushort4*)(W + (size_t)o * K_DIM + ii);
  Wo[0] = r0;
  Wo[1] = r1;
}

// ---------------------------------------------------------------------------
// Kernel 3: C[M][N] = A[M][K] * B[N][K]^T, bf16 in, f32 out
// BM=256 BN=128 BK=64, 4 waves, wave tile 128x64 (8x4 of 16x16x32 MFMA).
// Pipelined K-loop: A double-buffered in LDS via global_load_lds (prefetch
// issued a full compute-phase before its vmcnt(0) drain); B prefetched into
// registers and ds_written after barrier 1 (crosses the barrier in regs).
// Neither barrier has exposed global latency.
// ---------------------------------------------------------------------------
__global__ __launch_bounds__(256, 2) void gemm_kernel(
    const unsigned short* __restrict__ A,
    const unsigned short* __restrict__ B,
    float* __restrict__ C) {
  __shared__ unsigned short As[2 * BM * BK];  // 64 KB (double-buffered)
  __shared__ unsigned short Bs[BN * BK];      // 16 KB

  const int tid  = threadIdx.x;
  // XCD swizzle: dispatch order is linear id, id%8 ~ XCD. Give each XCD a
  // contiguous 4-slab M-range so its 64 co-resident blocks share A in L2.
  const int id  = blockIdx.y * 16 + blockIdx.x;
  const int nid = (id & 7) * 64 + (id >> 3);
  const int bm  = (nid >> 4) * BM;
  const int bn  = (nid & 15) * BN;

  const int lane = tid & 63;
  const int wv   = tid >> 6;
  const int waveM = (wv >> 1) * 128;
  const int waveN = (wv & 1) * 64;
  const int quad = lane >> 4;
  const int l16  = lane & 15;

  // --- A staging (global_load_lds): row = j*32 + (tid>>3),
  // global chunk (phys) = (tid&7) ^ (row&7), LDS slot = tid&7.
  const int trow = tid >> 3;                    // 0..31
  const int phys = (tid & 7) ^ (trow & 7);
  const unsigned short* ag = A + (size_t)(bm + trow) * K_DIM + phys * 8;

  // --- B staging (reg prefetch + ds_write): load global chunk c = tid&7,
  // write to slot c ^ (row&7)  -> same slot->chunk mapping as A's scheme.
  const unsigned short* bgp = B + (size_t)(bn + trow) * K_DIM + (tid & 7) * 8;
  int bwoff[4];
#pragma unroll
  for (int j = 0; j < 4; ++j) {
    const int row = trow + j * 32;
    bwoff[j] = row * BK + (((tid & 7) ^ (row & 7)) * 8);
  }

  // --- fragment read offsets (undo swizzle); row&7 == l16&7 for all frags
  int aoff[8], boff[4];
#pragma unroll
  for (int mi = 0; mi < 8; ++mi)
    aoff[mi] = (waveM + mi * 16 + l16) * BK + ((quad ^ (l16 & 7)) * 8);
#pragma unroll
  for (int ni = 0; ni < 4; ++ni)
    boff[ni] = (waveN + ni * 16 + l16) * BK + ((quad ^ (l16 & 7)) * 8);

  f32x4 acc[8][4] = {};
  s16x8 breg[4];

  // --- prologue: stage tile 0
#pragma unroll
  for (int j = 0; j < 8; ++j)
    __builtin_amdgcn_global_load_lds((const AS1 void*)(ag + (size_t)j * 32 * K_DIM),
                                     (AS3 void*)(&As[tid * 8 + j * 2048]), 16, 0, 0);
#pragma unroll
  for (int j = 0; j < 4; ++j)
    breg[j] = *(const s16x8*)(bgp + (size_t)j * 32 * K_DIM);
#pragma unroll
  for (int j = 0; j < 4; ++j)
    *(s16x8*)&Bs[bwoff[j]] = breg[j];
  __syncthreads();

  for (int k0 = 0; k0 < K_DIM; k0 += BK) {
    const int p  = (k0 >> 6) & 1;
    const int kn = k0 + BK;
    if (kn < K_DIM) {  // prefetch tile k+1 (block-uniform branch)
#pragma unroll
      for (int j = 0; j < 8; ++j)
        __builtin_amdgcn_global_load_lds(
            (const AS1 void*)(ag + (size_t)j * 32 * K_DIM + kn),
            (AS3 void*)(&As[((p ^ 1) << 14) + tid * 8 + j * 2048]), 16, 0, 0);
#pragma unroll
      for (int j = 0; j < 4; ++j)
        breg[j] = *(const s16x8*)(bgp + (size_t)j * 32 * K_DIM + kn);
    }

    // --- compute on tile k (As[p], Bs)
#pragma unroll
    for (int kk = 0; kk < 2; ++kk) {
      s16x8 af[8], bf[4];
#pragma unroll
      for (int mi = 0; mi < 8; ++mi)
        af[mi] = *(const s16x8*)&As[(p << 14) + (aoff[mi] ^ (kk * 32))];
#pragma unroll
      for (int ni = 0; ni < 4; ++ni)
        bf[ni] = *(const s16x8*)&Bs[boff[ni] ^ (kk * 32)];
#pragma unroll
      for (int mi = 0; mi < 8; ++mi)
#pragma unroll
        for (int ni = 0; ni < 4; ++ni)
          acc[mi][ni] = __builtin_amdgcn_mfma_f32_16x16x32_bf16(
              af[mi], bf[ni], acc[mi][ni], 0, 0, 0);
    }
    __syncthreads();   // drains A(k+1) glds + breg loads — both issued a full
                       // compute phase ago; also fences reads of Bs
    if (kn < K_DIM) {
#pragma unroll
      for (int j = 0; j < 4; ++j)
        *(s16x8*)&Bs[bwoff[j]] = breg[j];
    }
    __syncthreads();   // Bs(k+1) visible; lgkm-only, cheap
  }

  // --- epilogue: C/D layout col=lane&15, row=quad*4+reg
#pragma unroll
  for (int mi = 0; mi < 8; ++mi) {
#pragma unroll
    for (int ni = 0; ni < 4; ++ni) {
      const int o = bn + waveN + ni * 16 + l16;
#pragma unroll
      for (int r = 0; r < 4; ++r) {
        const int t = bm + waveM + mi * 16 + quad * 4 + r;
        C[(size_t)t * N_DIM + o] = acc[mi][ni][r];
      }
    }
  }
}

// ---------------------------------------------------------------------------
extern "C" void kernel_launch(void* const* d_in, const int* in_sizes, int n_in,
                              void* d_out, int out_size, void* d_ws, size_t ws_size,
                              hipStream_t stream) {
  const float* x        = (const float*)d_in[0];
  const int*   w_int    = (const int*)d_in[1];
  const float* w_scales = (const float*)d_in[2];
  const float* w_zeros  = (const float*)d_in[3];
  float* out = (float*)d_out;

  unsigned short* Aq = (unsigned short*)d_ws;                 // 8192*2048 bf16
  unsigned short* Wq = Aq + (size_t)M_DIM * K_DIM;            // 2048*2048 bf16

  quant_x_kernel<<<M_DIM, 256, 0, stream>>>(x, Aq);
  prep_w_kernel<<<(N_DIM * (K_DIM / 8)) / 256, 256, 0, stream>>>(w_int, w_scales, w_zeros, Wq);
  dim3 grid(N_DIM / BN, M_DIM / BM);
  gemm_kernel<<<grid, 256, 0, stream>>>(Aq, Wq, out);
}